// Round 4
// baseline (589.566 us; speedup 1.0000x reference)
//
#include <hip/hip_runtime.h>
#include <cstdint>

typedef __bf16 bf16_t;
typedef __attribute__((ext_vector_type(8))) __bf16 bf16x8;
typedef __attribute__((ext_vector_type(4))) float f32x4;

#define MC_EPS 1e-8f

__device__ __forceinline__ void async_ld16(const bf16_t* g, bf16_t* l) {
  __builtin_amdgcn_global_load_lds(
      (const __attribute__((address_space(1))) void*)g,
      (__attribute__((address_space(3))) void*)l, 16, 0, 0);
}

// s[b][ci] = dot(w[b,:], affine_w[ci,:]) + affine_b[ci] + 1
__global__ void s_kernel(const float* __restrict__ w, const float* __restrict__ aw,
                         const float* __restrict__ ab, float* __restrict__ s) {
  int ci = blockIdx.x, tid = threadIdx.x;
  int b = tid >> 4, part = tid & 15;
  const float* ar = aw + (ci << 9);
  const float* wr = w + (b << 9);
  float acc = 0.f;
  for (int j = part; j < 512; j += 16) acc += wr[j] * ar[j];
  for (int off = 8; off; off >>= 1) acc += __shfl_down(acc, off, 64);
  if (part == 0) s[(b << 9) + ci] = acc + ab[ci] + 1.0f;
}

// fused: wsq[co][ci] = sum_t w^2 ; w_t[t][co][ci] = bf16(w)
__global__ void prep_w_kernel(const float* __restrict__ wgt, float* __restrict__ wsq,
                              bf16_t* __restrict__ w_t) {
  int idx = blockIdx.x * 256 + threadIdx.x;  // co*512+ci
  const float* p = wgt + (size_t)idx * 9;
  float v[9];
  float a = 0.f;
#pragma unroll
  for (int j = 0; j < 9; ++j) { v[j] = p[j]; a += v[j] * v[j]; }
  wsq[idx] = a;
#pragma unroll
  for (int j = 0; j < 9; ++j) w_t[((size_t)j << 18) + idx] = (bf16_t)v[j];
}

// d[b][co] = rsqrt(sum_ci wsq[co][ci] * s[b][ci]^2 + eps)
__global__ void d_kernel(const float* __restrict__ wsq, const float* __restrict__ s,
                         float* __restrict__ d) {
  int co = blockIdx.x, tid = threadIdx.x;
  int b = tid >> 4, part = tid & 15;
  const float* wr = wsq + (co << 9);
  const float* sr = s + (b << 9);
  float acc = 0.f;
  for (int j = part; j < 512; j += 16) { float sv = sr[j]; acc += wr[j] * sv * sv; }
  for (int off = 8; off; off >>= 1) acc += __shfl_down(acc, off, 64);
  if (part == 0) d[(b << 9) + co] = rsqrtf(acc + MC_EPS);
}

// zero only the 1-px halo border of x_pad
__global__ void halo_kernel(bf16_t* __restrict__ xp) {
  int gid = blockIdx.x * 256 + threadIdx.x;
  if (gid >= 16 * 260 * 64) return;
  int cg = gid & 63;
  int p = (gid >> 6) % 260;
  int b = (gid >> 6) / 260;
  int h, w;
  if (p < 66)       { h = 0;       w = p; }
  else if (p < 132) { h = 65;      w = p - 66; }
  else if (p < 196) { h = p - 131; w = 0; }
  else              { h = p - 195; w = 65; }
  uint4 z = {0u, 0u, 0u, 0u};
  *(uint4*)&xp[((size_t)(b * 66 + h) * 66 + w) * 512 + (cg << 3)] = z;
}

// x_pad[b][h+1][w+1][ci] = bf16(x[b][ci][h][w] * s[b][ci])  (NHWC, 1-px halo)
__global__ void xmod_kernel(const float* __restrict__ x, const float* __restrict__ s,
                            bf16_t* __restrict__ xp) {
  int b = blockIdx.x >> 6, h = blockIdx.x & 63;
  int tid = threadIdx.x;
  __shared__ __align__(16) bf16_t tile[64 * 130];
  for (int c0 = 0; c0 < 512; c0 += 128) {
    if (c0) __syncthreads();
    int w4 = (tid & 15) << 2;
    int cl = tid >> 4;
#pragma unroll
    for (int r = 0; r < 8; ++r) {
      int ci = cl + (r << 4);
      const float4 v = *(const float4*)&x[(size_t)(((b << 9) + c0 + ci) << 12) + (h << 6) + w4];
      float sv = s[(b << 9) + c0 + ci];
      tile[(w4 + 0) * 130 + ci] = (bf16_t)(v.x * sv);
      tile[(w4 + 1) * 130 + ci] = (bf16_t)(v.y * sv);
      tile[(w4 + 2) * 130 + ci] = (bf16_t)(v.z * sv);
      tile[(w4 + 3) * 130 + ci] = (bf16_t)(v.w * sv);
    }
    __syncthreads();
#pragma unroll
    for (int it = 0; it < 4; ++it) {
      int i = tid + it * 256;
      int w = i >> 4, cg = i & 15;
      const uint32_t* tp = (const uint32_t*)&tile[w * 130 + (cg << 3)];
      uint4 v = { tp[0], tp[1], tp[2], tp[3] };
      *(uint4*)&xp[((size_t)(b * 66 + h + 1) * 66 + (w + 1)) * 512 + c0 + (cg << 3)] = v;
    }
  }
}

// Implicit-GEMM conv. Geometry change vs r3: 4 waves x 128x128 per wave
// (BM=256 px x BN=256 co, 2M x 2N wave grid). Fragment LDS reads scale with
// (Wm+Wn): 128x128 -> 16 KB/wave/tile x 4 waves = 64 KB vs r3's 96 KB; with
// 32 KB staging writes the LDS pipe needs ~1130 cyc/tile < MFMA 1242 cyc ->
// MFMA is now the binding pipe (r3 measured 2158 cyc/tile = LDS-bound 57%).
// Register double-buffer across the tile barrier kept from r3: during tile k,
// read tile k+1's fragments (16 ds_read_b128) + stage tile k+3 into slot
// (k-1)%4 + 64 MFMAs; boundary = counted vmcnt(8) (never drains) + s_barrier.
// Regs/wave: acc 8x8 f32x4 = 256 + frags 32 bf16x8 = 128 + addr ~30 => ~415,
// under the 450 no-spill line; 1 wave/SIMD. All indexing static (full unroll).
// Swizzle (verified 0-conflict): stage cig=(e&3)^((p>>1)&3), read
// phys=(quad^((lr>>1)&3))<<3. XCD swizzle: g&7 -> 32-mb slab/XCD.
#define RDFRAG(SB, FA, FB)                                                      \
  { const int sbb_ = (SB);                                                      \
    _Pragma("unroll") for (int nt = 0; nt < 8; ++nt)                            \
      FB[nt] = *(const bf16x8*)&smem[sbb_ + 8192 + ((brow + (nt << 4)) << 5) + phys]; \
    _Pragma("unroll") for (int mt = 0; mt < 8; ++mt)                            \
      FA[mt] = *(const bf16x8*)&smem[sbb_ + ((arow + (mt << 4)) << 5) + phys]; }

#define TILE_STEP(K, AR, BR, AW, BW)                                            \
  { const int k_ = (K);                                                         \
    if (k_ + 1 < 144) { RDFRAG(((k_ + 1) & 3) << 14, AW, BW) }                  \
    if (k_ + 3 < 144) {                                                         \
      const int kp_ = k_ + 3;                                                   \
      const int pb_ = (kp_ & 3) << 14;                                          \
      const int tp_ = kp_ >> 4;                                                 \
      const int kh_ = tp_ / 3, kw_ = tp_ - kh_ * 3;                             \
      const int ao_ = ((kh_ * 66 + kw_) << 9) + ((kp_ & 15) << 5);              \
      const int bo_ = (tp_ << 18) + ((kp_ & 15) << 5);                          \
      _Pragma("unroll") for (int j = 0; j < 4; ++j) {                           \
        async_ld16(xp + a_base[j] + ao_, &smem[pb_ + a_dst[j]]);                \
        async_ld16(w_t + b_base[j] + bo_, &smem[pb_ + b_dst[j]]);               \
      }                                                                         \
    }                                                                           \
    _Pragma("unroll") for (int mt = 0; mt < 8; ++mt)                            \
      _Pragma("unroll") for (int nt = 0; nt < 8; ++nt)                          \
        acc[mt][nt] = __builtin_amdgcn_mfma_f32_16x16x32_bf16(AR[mt], BR[nt], acc[mt][nt], 0, 0, 0); \
    if (k_ < 141) asm volatile("s_waitcnt vmcnt(8)" ::: "memory");              \
    else          asm volatile("s_waitcnt vmcnt(0)" ::: "memory");              \
    if (k_ < 143) __builtin_amdgcn_s_barrier(); }

__global__ __launch_bounds__(256, 1) void conv_kernel(
    const bf16_t* __restrict__ xp, const bf16_t* __restrict__ w_t,
    const float* __restrict__ d, float* __restrict__ out) {
  extern __shared__ bf16_t smem[];   // 4 slots x 16384 elems (A 8192 | B 8192) = 128 KB
  const int tid = threadIdx.x, lane = tid & 63;
  const int g = blockIdx.x;
  const int xcd = g & 7;
  const int slot = g >> 3;                  // 0..63
  const int mb = (xcd << 5) + (slot >> 1);  // 0..255
  const int nb = slot & 1;
  const int b = mb >> 4;
  const int h0 = (mb & 15) << 2;            // 4 output rows per block
  const int n0 = nb << 8;                   // 256 co per block
  const int wv = tid >> 6;
  const int wm = wv >> 1, wn = wv & 1;      // 2M x 2N, per-wave 128 px x 128 co
  const int quad = lane >> 4, lr = lane & 15;

  // per-thread staging invariants (4 A-loads + 4 B-loads per K-tile, 256 thr)
  int a_base[4], a_dst[4], b_base[4], b_dst[4];
#pragma unroll
  for (int j = 0; j < 4; ++j) {
    int e = (j << 8) + tid;                 // [0,1024)
    int p = e >> 2;                         // px / co row [0,256)
    int cig = (e & 3) ^ ((p >> 1) & 3);     // swizzled logical ci-group (8 elems)
    a_base[j] = ((b * 66 + h0 + (p >> 6)) * 66 + (p & 63)) * 512 + (cig << 3);
    a_dst[j] = (e & ~63) << 3;              // wave-uniform linear dest
    b_base[j] = ((n0 + p) << 9) + (cig << 3);
    b_dst[j] = 8192 + a_dst[j];
  }

  f32x4 acc[8][8];
#pragma unroll
  for (int i = 0; i < 8; ++i)
#pragma unroll
    for (int j = 0; j < 8; ++j) acc[i][j] = (f32x4){0.f, 0.f, 0.f, 0.f};

  // prologue: stage tiles 0..2 (tap 0, ci0 = kt*32) into slots 0..2
#pragma unroll
  for (int kt = 0; kt < 3; ++kt) {
    const int cio = kt << 5;
    const int sb = kt << 14;
#pragma unroll
    for (int j = 0; j < 4; ++j) {
      async_ld16(xp + a_base[j] + cio, &smem[sb + a_dst[j]]);
      async_ld16(w_t + b_base[j] + cio, &smem[sb + b_dst[j]]);
    }
  }
  asm volatile("s_waitcnt vmcnt(8)" ::: "memory");   // tiles 0,1 landed; 2 in flight
  __builtin_amdgcn_s_barrier();

  const int arow = (wm << 7) + lr;
  const int brow = (wn << 7) + lr;
  const int phys = (quad ^ ((lr >> 1) & 3)) << 3;

  bf16x8 fa0[8], fb0[8], fa1[8], fb1[8];
  RDFRAG(0, fa0, fb0)                        // fragments of tile 0

  for (int kk = 0; kk < 72; ++kk) {
    TILE_STEP(2 * kk,     fa0, fb0, fa1, fb1)
    TILE_STEP(2 * kk + 1, fa1, fb1, fa0, fb0)
  }

  // epilogue: out[b][co][h][w] = acc * d[b][co]
#pragma unroll
  for (int nt = 0; nt < 8; ++nt) {
    const int n = n0 + (wn << 7) + (nt << 4) + lr;
    const float dv = d[(b << 9) + n];
#pragma unroll
    for (int mt = 0; mt < 8; ++mt) {
#pragma unroll
      for (int r = 0; r < 4; ++r) {
        int m = (wm << 7) + (mt << 4) + (quad << 2) + r;   // pixel in tile [0,256)
        int h = h0 + (m >> 6), w = m & 63;
        out[((size_t)((b << 9) + n) << 12) + (h << 6) + w] = acc[mt][nt][r] * dv;
      }
    }
  }
}

extern "C" void kernel_launch(void* const* d_in, const int* in_sizes, int n_in,
                              void* d_out, int out_size, void* d_ws, size_t ws_size,
                              hipStream_t stream) {
  const float* x      = (const float*)d_in[0];   // [16,512,64,64]
  const float* w      = (const float*)d_in[1];   // [16,512]
  const float* weight = (const float*)d_in[2];   // [512,512,3,3]
  const float* aw     = (const float*)d_in[3];   // [512,512]
  const float* ab     = (const float*)d_in[4];   // [512]
  float* out = (float*)d_out;

  char* ws = (char*)d_ws;
  const size_t XP_BYTES  = (size_t)16 * 66 * 66 * 512 * 2;  // 71,368,704
  const size_t WT_BYTES  = (size_t)9 * 512 * 512 * 2;       //  4,718,592
  bf16_t* xp   = (bf16_t*)ws;
  bf16_t* w_t  = (bf16_t*)(ws + XP_BYTES);
  float*  s    = (float*)(ws + XP_BYTES + WT_BYTES);
  float*  wsq  = (float*)(ws + XP_BYTES + WT_BYTES + 32768);
  float*  dbuf = (float*)(ws + XP_BYTES + WT_BYTES + 32768 + 1048576);

  static int attr_done = 0;
  if (!attr_done) {
    hipFuncSetAttribute(reinterpret_cast<const void*>(conv_kernel),
                        hipFuncAttributeMaxDynamicSharedMemorySize, 131072);
    attr_done = 1;
  }

  halo_kernel<<<1040, 256, 0, stream>>>(xp);
  s_kernel<<<512, 256, 0, stream>>>(w, aw, ab, s);
  prep_w_kernel<<<1024, 256, 0, stream>>>(weight, wsq, w_t);
  d_kernel<<<512, 256, 0, stream>>>(wsq, s, dbuf);
  xmod_kernel<<<1024, 256, 0, stream>>>(x, s, xp);
  conv_kernel<<<512, 256, 131072, stream>>>(xp, w_t, dbuf, out);
}

// Round 5
// 505.516 us; speedup vs baseline: 1.1663x; 1.1663x over previous
//
#include <hip/hip_runtime.h>
#include <cstdint>

typedef __bf16 bf16_t;
typedef __attribute__((ext_vector_type(8))) __bf16 bf16x8;
typedef __attribute__((ext_vector_type(4))) float f32x4;

#define MC_EPS 1e-8f

__device__ __forceinline__ void async_ld16(const bf16_t* g, bf16_t* l) {
  __builtin_amdgcn_global_load_lds(
      (const __attribute__((address_space(1))) void*)g,
      (__attribute__((address_space(3))) void*)l, 16, 0, 0);
}

// s[b][ci] = dot(w[b,:], affine_w[ci,:]) + affine_b[ci] + 1
__global__ void s_kernel(const float* __restrict__ w, const float* __restrict__ aw,
                         const float* __restrict__ ab, float* __restrict__ s) {
  int ci = blockIdx.x, tid = threadIdx.x;
  int b = tid >> 4, part = tid & 15;
  const float* ar = aw + (ci << 9);
  const float* wr = w + (b << 9);
  float acc = 0.f;
  for (int j = part; j < 512; j += 16) acc += wr[j] * ar[j];
  for (int off = 8; off; off >>= 1) acc += __shfl_down(acc, off, 64);
  if (part == 0) s[(b << 9) + ci] = acc + ab[ci] + 1.0f;
}

// fused: wsq[co][ci] = sum_t w^2 ; w_t[t][co][ci] = bf16(w)
__global__ void prep_w_kernel(const float* __restrict__ wgt, float* __restrict__ wsq,
                              bf16_t* __restrict__ w_t) {
  int idx = blockIdx.x * 256 + threadIdx.x;  // co*512+ci
  const float* p = wgt + (size_t)idx * 9;
  float v[9];
  float a = 0.f;
#pragma unroll
  for (int j = 0; j < 9; ++j) { v[j] = p[j]; a += v[j] * v[j]; }
  wsq[idx] = a;
#pragma unroll
  for (int j = 0; j < 9; ++j) w_t[((size_t)j << 18) + idx] = (bf16_t)v[j];
}

// d[b][co] = rsqrt(sum_ci wsq[co][ci] * s[b][ci]^2 + eps)
__global__ void d_kernel(const float* __restrict__ wsq, const float* __restrict__ s,
                         float* __restrict__ d) {
  int co = blockIdx.x, tid = threadIdx.x;
  int b = tid >> 4, part = tid & 15;
  const float* wr = wsq + (co << 9);
  const float* sr = s + (b << 9);
  float acc = 0.f;
  for (int j = part; j < 512; j += 16) { float sv = sr[j]; acc += wr[j] * sv * sv; }
  for (int off = 8; off; off >>= 1) acc += __shfl_down(acc, off, 64);
  if (part == 0) d[(b << 9) + co] = rsqrtf(acc + MC_EPS);
}

// zero only the 1-px halo border of x_pad
__global__ void halo_kernel(bf16_t* __restrict__ xp) {
  int gid = blockIdx.x * 256 + threadIdx.x;
  if (gid >= 16 * 260 * 64) return;
  int cg = gid & 63;
  int p = (gid >> 6) % 260;
  int b = (gid >> 6) / 260;
  int h, w;
  if (p < 66)       { h = 0;       w = p; }
  else if (p < 132) { h = 65;      w = p - 66; }
  else if (p < 196) { h = p - 131; w = 0; }
  else              { h = p - 195; w = 65; }
  uint4 z = {0u, 0u, 0u, 0u};
  *(uint4*)&xp[((size_t)(b * 66 + h) * 66 + w) * 512 + (cg << 3)] = z;
}

// x_pad[b][h+1][w+1][ci] = bf16(x[b][ci][h][w] * s[b][ci])  (NHWC, 1-px halo)
__global__ void xmod_kernel(const float* __restrict__ x, const float* __restrict__ s,
                            bf16_t* __restrict__ xp) {
  int b = blockIdx.x >> 6, h = blockIdx.x & 63;
  int tid = threadIdx.x;
  __shared__ __align__(16) bf16_t tile[64 * 130];
  for (int c0 = 0; c0 < 512; c0 += 128) {
    if (c0) __syncthreads();
    int w4 = (tid & 15) << 2;
    int cl = tid >> 4;
#pragma unroll
    for (int r = 0; r < 8; ++r) {
      int ci = cl + (r << 4);
      const float4 v = *(const float4*)&x[(size_t)(((b << 9) + c0 + ci) << 12) + (h << 6) + w4];
      float sv = s[(b << 9) + c0 + ci];
      tile[(w4 + 0) * 130 + ci] = (bf16_t)(v.x * sv);
      tile[(w4 + 1) * 130 + ci] = (bf16_t)(v.y * sv);
      tile[(w4 + 2) * 130 + ci] = (bf16_t)(v.z * sv);
      tile[(w4 + 3) * 130 + ci] = (bf16_t)(v.w * sv);
    }
    __syncthreads();
#pragma unroll
    for (int it = 0; it < 4; ++it) {
      int i = tid + it * 256;
      int w = i >> 4, cg = i & 15;
      const uint32_t* tp = (const uint32_t*)&tile[w * 130 + (cg << 3)];
      uint4 v = { tp[0], tp[1], tp[2], tp[3] };
      *(uint4*)&xp[((size_t)(b * 66 + h + 1) * 66 + (w + 1)) * 512 + c0 + (cg << 3)] = v;
    }
  }
}

// Implicit-GEMM conv, m201-style 4-phase schedule. BM=256 px x BN=256 co,
// BK=64 (72 K-tiles), 8 waves (2M x 4N, 128x64/wave), 2 LDS bufs x 64 KB.
// Per K-tile, 4 phases = C-quadrants in Gray order (qm,qn): 00->01->11->10,
// carrying one operand in regs (24 b128/wave/tile = minimal). Per phase:
// {ds_read subtile; stage 1 chunk (2 gloads) -> other buf; barrier; lgkm(0);
//  setprio(1); 16 MFMA; setprio(0); counted vmcnt; barrier}. Staging chunks
// are wave-aligned: A-chunk-q = qm-half of EACH wm strip (px rows {0-63,
// 128-191} / {64-127,192-255}), B-chunk-q = qn-half of each wn strip, so
// phase (qm,qn) needs exactly chunks A-qm,B-qn for all waves -> vmcnt(4) is
// exact and never drains (except last tile: 2/0). vmcnt precedes the CLOSING
// barrier so the barrier broadcasts per-wave load completion cross-wave.
// Buffer reuse: each overwritten region's last read retired >=2 barriers
// earlier (chunk X(t+1) staged at phase p(t); X(t-1) read at phase p(t-1)).
// Swizzle (r0-verified, 0 conflicts): store logical k-group g at g^(row&7);
// read phys = ((ks*4+quad)^(lr&7)). XCD swizzle: g&7 -> 32-mb slab/XCD.
#define RD_A(QM)                                                                \
  _Pragma("unroll") for (int mt = 0; mt < 4; ++mt)                              \
    _Pragma("unroll") for (int ks = 0; ks < 2; ++ks)                            \
      fa[mt * 2 + ks] = *(const bf16x8*)&smem[cb +                              \
        (((wm << 7) + ((QM) << 6) + (mt << 4) + lr) << 6) +                     \
        ((((ks << 2) | quad) ^ lr7) << 3)];

#define RD_B(QN, FB)                                                            \
  _Pragma("unroll") for (int nt = 0; nt < 2; ++nt)                              \
    _Pragma("unroll") for (int ks = 0; ks < 2; ++ks)                            \
      FB[nt * 2 + ks] = *(const bf16x8*)&smem[cb + 16384 +                      \
        (((wn << 6) + ((QN) << 5) + (nt << 4) + lr) << 6) +                     \
        ((((ks << 2) | quad) ^ lr7) << 3)];

#define ST_A(C)                                                                 \
  if (pf) { async_ld16(xp + aab[C][0] + aoff, &smem[ob + aad[C][0]]);           \
            async_ld16(xp + aab[C][1] + aoff, &smem[ob + aad[C][1]]); }

#define ST_B(C)                                                                 \
  if (pf) { async_ld16(w_t + bbb[C][0] + boff, &smem[ob + bbd[C][0]]);          \
            async_ld16(w_t + bbb[C][1] + boff, &smem[ob + bbd[C][1]]); }

#define MM(FB, RB, CB)                                                          \
  _Pragma("unroll") for (int mt = 0; mt < 4; ++mt)                              \
    _Pragma("unroll") for (int nt = 0; nt < 2; ++nt)                            \
      _Pragma("unroll") for (int ks = 0; ks < 2; ++ks)                          \
        acc[(RB) + mt][(CB) + nt] = __builtin_amdgcn_mfma_f32_16x16x32_bf16(    \
            fa[mt * 2 + ks], FB[nt * 2 + ks], acc[(RB) + mt][(CB) + nt], 0, 0, 0);

#define BAR1()                                                                  \
  __builtin_amdgcn_s_barrier();                                                 \
  asm volatile("s_waitcnt lgkmcnt(0)" ::: "memory");                            \
  __builtin_amdgcn_sched_barrier(0);                                            \
  __builtin_amdgcn_s_setprio(1);

__global__ __launch_bounds__(512, 1) void conv_kernel(
    const bf16_t* __restrict__ xp, const bf16_t* __restrict__ w_t,
    const float* __restrict__ d, float* __restrict__ out) {
  extern __shared__ bf16_t smem[];   // 2 bufs x 32768 el (A 16384 | B 16384) = 128 KB
  const int tid = threadIdx.x, lane = tid & 63;
  const int g = blockIdx.x;
  const int xcd = g & 7;
  const int slot = g >> 3;                  // 0..63
  const int mb = (xcd << 5) + (slot >> 1);  // 0..255
  const int nb = slot & 1;
  const int b = mb >> 4;
  const int h0 = (mb & 15) << 2;            // 4 output rows per block
  const int n0 = nb << 8;                   // 256 co per block
  const int wv = tid >> 6;
  const int wm = wv >> 2, wn = wv & 3;      // 2M x 4N, per-wave 128 px x 64 co
  const int quad = lane >> 4, lr = lane & 15, lr7 = lr & 7;

  // per-thread staging invariants: chunk c of A/B, 2 loads each
  int aab[2][2], aad[2][2], bbb[2][2], bbd[2][2];
#pragma unroll
  for (int c = 0; c < 2; ++c)
#pragma unroll
    for (int j = 0; j < 2; ++j) {
      int e = (j << 9) + tid;               // [0,1024)
      int r = e >> 3;                       // chunk row [0,128)
      int cig = e & 7;                      // linear 16B slot in 128B row
      int kk = cig ^ (r & 7);               // logical k-group stored here
      int px = ((r >> 6) << 7) + (c << 6) + (r & 63);   // A: qm-half of each wm strip
      aab[c][j] = ((b * 66 + h0 + (px >> 6)) * 66 + (px & 63)) * 512 + (kk << 3);
      aad[c][j] = (px << 6) + (cig << 3);
      int co = ((r >> 5) << 6) + (c << 5) + (r & 31);   // B: qn-half of each wn strip
      bbb[c][j] = ((n0 + co) << 9) + (kk << 3);
      bbd[c][j] = 16384 + (co << 6) + (cig << 3);
    }

  f32x4 acc[8][4];
#pragma unroll
  for (int i = 0; i < 8; ++i)
#pragma unroll
    for (int j = 0; j < 4; ++j) acc[i][j] = (f32x4){0.f, 0.f, 0.f, 0.f};

  // prologue: stage tile 0 (tap 0, ci0 0) into buf 0, order A0,B0,B1,A1
  {
    const bool pf = true; const int ob = 0, aoff = 0, boff = 0;
    ST_A(0) ST_B(0) ST_B(1) ST_A(1)
  }
  asm volatile("s_waitcnt vmcnt(4)" ::: "memory");   // A0,B0 landed; B1,A1 in flight
  __builtin_amdgcn_s_barrier();

  bf16x8 fa[8], fb0[4], fb1[4];

  for (int t = 0; t < 72; ++t) {
    const int cb = (t & 1) << 15;
    const int ob = cb ^ 32768;
    const int tn = t + 1;
    const bool pf = tn < 72;
    const int tap = tn >> 3;
    const int kh = tap / 3, kw = tap - kh * 3;
    const int ci0 = (tn & 7) << 6;
    const int aoff = ((kh * 66 + kw) << 9) + ci0;
    const int boff = (tap << 18) + ci0;

    // ---- phase 1: quadrant (0,0); reads A0(8)+B0(4); stage A0(t+1) ----
    RD_A(0) RD_B(0, fb0)
    ST_A(0)
    BAR1()
    MM(fb0, 0, 0)
    __builtin_amdgcn_s_setprio(0);
    if (t < 71) asm volatile("s_waitcnt vmcnt(4)" ::: "memory");
    else        asm volatile("s_waitcnt vmcnt(2)" ::: "memory");
    __builtin_amdgcn_s_barrier();

    // ---- phase 2: quadrant (0,1); reads B1(4); stage B0(t+1) ----
    RD_B(1, fb1)
    ST_B(0)
    BAR1()
    MM(fb1, 0, 2)
    __builtin_amdgcn_s_setprio(0);
    if (t < 71) asm volatile("s_waitcnt vmcnt(4)" ::: "memory");
    else        asm volatile("s_waitcnt vmcnt(0)" ::: "memory");
    __builtin_amdgcn_s_barrier();

    // ---- phase 3: quadrant (1,1); reads A1(8); stage B1(t+1) ----
    RD_A(1)
    ST_B(1)
    BAR1()
    MM(fb1, 4, 2)
    __builtin_amdgcn_s_setprio(0);
    __builtin_amdgcn_s_barrier();

    // ---- phase 4: quadrant (1,0); no reads (operands carried); stage A1(t+1) ----
    ST_A(1)
    __builtin_amdgcn_s_barrier();
    __builtin_amdgcn_s_setprio(1);
    MM(fb0, 4, 0)
    __builtin_amdgcn_s_setprio(0);
    if (t < 71) asm volatile("s_waitcnt vmcnt(4)" ::: "memory");
    __builtin_amdgcn_s_barrier();
  }

  // epilogue: out[b][co][h][w] = acc * d[b][co]
#pragma unroll
  for (int nt = 0; nt < 4; ++nt) {
    const int n = n0 + (wn << 6) + (nt << 4) + lr;
    const float dv = d[(b << 9) + n];
#pragma unroll
    for (int mt = 0; mt < 8; ++mt) {
#pragma unroll
      for (int r = 0; r < 4; ++r) {
        int m = (wm << 7) + (mt << 4) + (quad << 2) + r;   // pixel in tile [0,256)
        int h = h0 + (m >> 6), w = m & 63;
        out[((size_t)((b << 9) + n) << 12) + (h << 6) + w] = acc[mt][nt][r] * dv;
      }
    }
  }
}

extern "C" void kernel_launch(void* const* d_in, const int* in_sizes, int n_in,
                              void* d_out, int out_size, void* d_ws, size_t ws_size,
                              hipStream_t stream) {
  const float* x      = (const float*)d_in[0];   // [16,512,64,64]
  const float* w      = (const float*)d_in[1];   // [16,512]
  const float* weight = (const float*)d_in[2];   // [512,512,3,3]
  const float* aw     = (const float*)d_in[3];   // [512,512]
  const float* ab     = (const float*)d_in[4];   // [512]
  float* out = (float*)d_out;

  char* ws = (char*)d_ws;
  const size_t XP_BYTES  = (size_t)16 * 66 * 66 * 512 * 2;  // 71,368,704
  const size_t WT_BYTES  = (size_t)9 * 512 * 512 * 2;       //  4,718,592
  bf16_t* xp   = (bf16_t*)ws;
  bf16_t* w_t  = (bf16_t*)(ws + XP_BYTES);
  float*  s    = (float*)(ws + XP_BYTES + WT_BYTES);
  float*  wsq  = (float*)(ws + XP_BYTES + WT_BYTES + 32768);
  float*  dbuf = (float*)(ws + XP_BYTES + WT_BYTES + 32768 + 1048576);

  static int attr_done = 0;
  if (!attr_done) {
    hipFuncSetAttribute(reinterpret_cast<const void*>(conv_kernel),
                        hipFuncAttributeMaxDynamicSharedMemorySize, 131072);
    attr_done = 1;
  }

  halo_kernel<<<1040, 256, 0, stream>>>(xp);
  s_kernel<<<512, 256, 0, stream>>>(w, aw, ab, s);
  prep_w_kernel<<<1024, 256, 0, stream>>>(weight, wsq, w_t);
  d_kernel<<<512, 256, 0, stream>>>(wsq, s, dbuf);
  xmod_kernel<<<1024, 256, 0, stream>>>(x, s, xp);
  conv_kernel<<<512, 512, 131072, stream>>>(xp, w_t, dbuf, out);
}